// Round 4
// baseline (246.192 us; speedup 1.0000x reference)
//
#include <hip/hip_runtime.h>
#include <hip/hip_bf16.h>

// M=2048, A=64, E=128, H=256, bond types=4, atom types=118
typedef __bf16 bf16x8 __attribute__((ext_vector_type(8)));
typedef float f32x16 __attribute__((ext_vector_type(16)));

__device__ inline unsigned short f2bf(float f) {
  __hip_bfloat16 h = __float2bfloat16(f);
  return *reinterpret_cast<unsigned short*>(&h);
}
__device__ inline unsigned pack2bf(float a, float b) {
  return (unsigned)f2bf(a) | ((unsigned)f2bf(b) << 16);
}
__device__ inline uint2 pack4bf(float a, float b, float c, float d) {
  uint2 r; r.x = pack2bf(a, b); r.y = pack2bf(c, d); return r;
}
__device__ inline bf16x8 as_bf16x8(uint4 v) { return __builtin_bit_cast(bf16x8, v); }
__device__ inline float bitf(unsigned u) { return __builtin_bit_cast(float, u); }
__device__ inline f32x16 mfma16(bf16x8 a, bf16x8 b, f32x16 c) {
  return __builtin_amdgcn_mfma_f32_32x32x16_bf16(a, b, c, 0, 0, 0);
}

// LDS addr of X/h element: row (R*32+l31), k-chunk KK, half h; XOR row-swizzle.
#define BADDR(XB, R, KK)                                                       \
  ((XB) + (((((R) * 32 + l31) << 9) + ((KK) << 5) + (h << 4)) ^ swz))

// 64-row x 64-col per-wave GEMM over K=256. 2 A-tiles + 2 B-frags per kk,
// depth-1 ping-pong prefetch, named regs only. Writes acc00,acc10,acc01,acc11:
// acc{C}{R}: C = col-tile (W cols CW_+C*32), R = row-tile (X rows R*32..).
#define GEMM22(XB, WPTR, CW_)                                                  \
  {                                                                            \
    const unsigned char* wb_ = (const unsigned char*)(WPTR) +                  \
                               (((CW_) + l31) << 5) + (h << 4);                \
    acc00 = zero; acc01 = zero; acc10 = zero; acc11 = zero;                    \
    bf16x8 pB0 = *(const bf16x8*)BADDR(XB, 0, 0);                              \
    bf16x8 pB1 = *(const bf16x8*)BADDR(XB, 1, 0);                              \
    uint4 pA0 = *(const uint4*)(wb_ + 0);                                      \
    uint4 pA1 = *(const uint4*)(wb_ + 1024);                                   \
    _Pragma("unroll")                                                          \
    for (int kk = 0; kk < 16; kk += 2) {                                       \
      bf16x8 qB0 = *(const bf16x8*)BADDR(XB, 0, kk + 1);                       \
      bf16x8 qB1 = *(const bf16x8*)BADDR(XB, 1, kk + 1);                       \
      uint4 qA0 = *(const uint4*)(wb_ + ((kk + 1) << 13));                     \
      uint4 qA1 = *(const uint4*)(wb_ + ((kk + 1) << 13) + 1024);              \
      acc00 = mfma16(as_bf16x8(pA0), pB0, acc00);                              \
      acc10 = mfma16(as_bf16x8(pA1), pB0, acc10);                              \
      acc01 = mfma16(as_bf16x8(pA0), pB1, acc01);                              \
      acc11 = mfma16(as_bf16x8(pA1), pB1, acc11);                              \
      if (kk + 2 < 16) {                                                       \
        pB0 = *(const bf16x8*)BADDR(XB, 0, kk + 2);                            \
        pB1 = *(const bf16x8*)BADDR(XB, 1, kk + 2);                            \
        pA0 = *(const uint4*)(wb_ + ((kk + 2) << 13));                         \
        pA1 = *(const uint4*)(wb_ + ((kk + 2) << 13) + 1024);                  \
      }                                                                        \
      acc00 = mfma16(as_bf16x8(qA0), qB0, acc00);                              \
      acc10 = mfma16(as_bf16x8(qA1), qB0, acc10);                              \
      acc01 = mfma16(as_bf16x8(qA0), qB1, acc01);                              \
      acc11 = mfma16(as_bf16x8(qA1), qB1, acc11);                              \
    }                                                                          \
  }

// write one 32x32 tile: rows (R*32+l31), cols (CW_+C*32..+31), bias+relu
#define WB22(DB, ACC, R, C, CW_, BIASPTR)                                      \
  _Pragma("unroll")                                                            \
  for (int g = 0; g < 4; ++g) {                                                \
    int xr_ = (R) * 32 + l31;                                                  \
    int col = (CW_) + (C) * 32 + g * 8 + h * 4;                                \
    float4 bb = *(const float4*)((BIASPTR) + col);                             \
    float v0 = fmaxf(ACC[4 * g + 0] + bb.x, 0.f);                              \
    float v1 = fmaxf(ACC[4 * g + 1] + bb.y, 0.f);                              \
    float v2 = fmaxf(ACC[4 * g + 2] + bb.z, 0.f);                              \
    float v3 = fmaxf(ACC[4 * g + 3] + bb.w, 0.f);                              \
    int off = ((xr_ << 9) + (col << 1)) ^ ((xr_ & 7) << 4);                    \
    *(uint2*)((DB) + off) = pack4bf(v0, v1, v2, v3);                           \
  }

#define WB22R(DB, ACC, R, C, CW_)                                              \
  _Pragma("unroll")                                                            \
  for (int g = 0; g < 4; ++g) {                                                \
    int xr_ = (R) * 32 + l31;                                                  \
    int col = (CW_) + (C) * 32 + g * 8 + h * 4;                                \
    int off = ((xr_ << 9) + (col << 1)) ^ ((xr_ & 7) << 4);                    \
    *(uint2*)((DB) + off) = pack4bf(ACC[4 * g + 0], ACC[4 * g + 1],            \
                                    ACC[4 * g + 2], ACC[4 * g + 3]);           \
  }

// f32 staging: 64x256 f32 -> bf16 LDS, row-swizzled (8 iters of 256 threads)
#define STAGE_X(DST, SRC)                                                      \
  _Pragma("unroll")                                                            \
  for (int it = 0; it < 8; ++it) {                                             \
    int lb = (it * 256 + tid) * 16;                                            \
    int d_ = lb ^ (((lb >> 9) & 7) << 4);                                      \
    const float4* s4 = (const float4*)((SRC) + (lb >> 1));                     \
    float4 f0 = s4[0], f1 = s4[1];                                             \
    uint4 v_ = { pack2bf(f0.x, f0.y), pack2bf(f0.z, f0.w),                     \
                 pack2bf(f1.x, f1.y), pack2bf(f1.z, f1.w) };                   \
    *(uint4*)((DST) + d_) = v_;                                                \
  }

// ---------------------------------------------------------------------------
// Pack Wp1 / Wa1 / Wa2 to bf16 fragment layout: ushort[(kk*N + n)*16 + dk]
// ---------------------------------------------------------------------------
__global__ __launch_bounds__(256) void k_pack(
    const float* __restrict__ wp1, const float* __restrict__ wa1,
    const float* __restrict__ wa2,
    unsigned short* __restrict__ dp1, unsigned short* __restrict__ da1,
    unsigned short* __restrict__ da2, float* __restrict__ accum)
{
  int b = blockIdx.x, tid = threadIdx.x;
  if (b == 0 && tid < 8) accum[tid] = 0.f;
  const float* src; unsigned short* dst; int e, logN, Nreal;
  if (b < 256)       { src = wp1; dst = dp1; e = b * 256 + tid;          logN = 8; Nreal = 256; }
  else if (b < 512)  { src = wa1; dst = da1; e = (b - 256) * 256 + tid;  logN = 8; Nreal = 256; }
  else               { src = wa2; dst = da2; e = (b - 512) * 256 + tid;  logN = 7; Nreal = 118; }
  int dk = e & 15;
  int rest = e >> 4;
  int n = rest & ((1 << logN) - 1);
  int kk = rest >> logN;
  int k = kk * 16 + dk;
  float v = (n < Nreal) ? src[k * Nreal + n] : 0.f;
  dst[e] = f2bf(v);
}

// ---------------------------------------------------------------------------
// Fold: Wct = Wp2 @ Wb1[0:256,:], Wcb = Wp2 @ Wb1[256:512,:]  (packed bf16)
//       bias_e = bp2 @ (Wb1t+Wb1b) + bb1
// ---------------------------------------------------------------------------
__global__ __launch_bounds__(256) void k_fold(
    const float* __restrict__ wp2, const float* __restrict__ wb1,
    const float* __restrict__ bp2, const float* __restrict__ bb1,
    unsigned short* __restrict__ dct, unsigned short* __restrict__ dcb,
    float* __restrict__ bias_e)
{
  int b = blockIdx.x, n = threadIdx.x;
  if (b < 512) {
    int k = b & 255;
    int off = (b < 256) ? 0 : 256;
    float s = 0.f;
    for (int t = 0; t < 256; ++t)
      s += wp2[k * 256 + t] * wb1[(t + off) * 256 + n];
    unsigned short* dst = (b < 256) ? dct : dcb;
    dst[((k >> 4) * 256 + n) * 16 + (k & 15)] = f2bf(s);
  } else {
    float s = bb1[n];
    for (int t = 0; t < 256; ++t)
      s += bp2[t] * (wb1[t * 256 + n] + wb1[(256 + t) * 256 + n]);
    bias_e[n] = s;
  }
}

// ---------------------------------------------------------------------------
// Fused bond kernel: one molecule (64 atoms, 128 edges) per block, 4 waves.
// Wave w handles cols w*64..+63, all 64 rows, in every GEMM.
// bufA: X -> h1 (in-place) -> he (in-place);  bufB: hs.
// ---------------------------------------------------------------------------
__global__ __launch_bounds__(256, 2) void k_bond(
    const float* __restrict__ node, const int* __restrict__ eidx,
    const int* __restrict__ tgt,
    const unsigned short* __restrict__ wp1p, const float* __restrict__ bp1,
    const unsigned short* __restrict__ wctp, const unsigned short* __restrict__ wcbp,
    const float* __restrict__ bias_e, const float* __restrict__ wb2,
    const float* __restrict__ bb2, float* __restrict__ accum)
{
  __shared__ __align__(16) unsigned char bufA[32768];
  __shared__ __align__(16) unsigned char bufB[32768];
  __shared__ float s_bias[256];
  __shared__ float4 s_wb2[256];
  __shared__ float s_red[8];
  const int tid = threadIdx.x;
  const int lane = tid & 63;
  const int w = tid >> 6;
  const int l31 = lane & 31;
  const int h = lane >> 5;
  const int swz = (l31 & 7) << 4;
  const int CW = w * 64;
  const int m = blockIdx.x;

  STAGE_X(bufA, node + (long)m * 16384);
  s_bias[tid] = bias_e[tid];
  s_wb2[tid] = ((const float4*)wb2)[tid];
  __syncthreads();                 // b1: staging visible

  f32x16 zero = {};
  f32x16 acc00, acc01, acc10, acc11;

  GEMM22(bufA, wp1p, CW);          // h1 pre-act
  __syncthreads();                 // b2: all X reads done
  WB22(bufA, acc00, 0, 0, CW, bp1);
  WB22(bufA, acc10, 0, 1, CW, bp1);
  WB22(bufA, acc01, 1, 0, CW, bp1);
  WB22(bufA, acc11, 1, 1, CW, bp1);
  __syncthreads();                 // b3: h1 visible

  GEMM22(bufA, wctp, CW);          // hs
  WB22R(bufB, acc00, 0, 0, CW);
  WB22R(bufB, acc10, 0, 1, CW);
  WB22R(bufB, acc01, 1, 0, CW);
  WB22R(bufB, acc11, 1, 1, CW);
  GEMM22(bufA, wcbp, CW);          // he (in regs)
  // prefetch edge metadata while he writeback drains
  const int es = eidx[m * 256 + (tid >> 1)];
  const int ed = eidx[m * 256 + 128 + (tid >> 1)];
  const int etg = tgt[m * 128 + (tid >> 1)];
  const float b20 = bb2[0], b21 = bb2[1], b22 = bb2[2], b23 = bb2[3];
  __syncthreads();                 // b4: all h1 reads done
  WB22R(bufA, acc00, 0, 0, CW);
  WB22R(bufA, acc10, 0, 1, CW);
  WB22R(bufA, acc01, 1, 0, CW);
  WB22R(bufA, acc11, 1, 1, CW);
  __syncthreads();                 // b5: hs/he visible

  // ---- edge phase: thread pair (2t,2t+1) -> edge t, col-halves ----
  {
    const int hf = tid & 1;
    float lg0 = 0.f, lg1 = 0.f, lg2 = 0.f, lg3 = 0.f;
    #pragma unroll
    for (int j = 0; j < 16; ++j) {
      int c0 = hf * 128 + j * 8;
      int offS = ((es << 9) + (c0 << 1)) ^ ((es & 7) << 4);
      int offD = ((ed << 9) + (c0 << 1)) ^ ((ed & 7) << 4);
      uint4 us = *(const uint4*)(bufB + offS);
      uint4 ud = *(const uint4*)(bufA + offD);
      const unsigned* pu = (const unsigned*)&us;
      const unsigned* pv = (const unsigned*)&ud;
      #pragma unroll
      for (int q = 0; q < 4; ++q) {
        unsigned ua = pu[q], ub = pv[q];
        int c = c0 + 2 * q;
        float hlo = bitf(ua << 16) + bitf(ub << 16) + s_bias[c];
        float hhi = bitf(ua & 0xffff0000u) + bitf(ub & 0xffff0000u) + s_bias[c + 1];
        hlo = fmaxf(hlo, 0.f); hhi = fmaxf(hhi, 0.f);
        float4 w0 = s_wb2[c], w1 = s_wb2[c + 1];
        lg0 = fmaf(hlo, w0.x, fmaf(hhi, w1.x, lg0));
        lg1 = fmaf(hlo, w0.y, fmaf(hhi, w1.y, lg1));
        lg2 = fmaf(hlo, w0.z, fmaf(hhi, w1.z, lg2));
        lg3 = fmaf(hlo, w0.w, fmaf(hhi, w1.w, lg3));
      }
    }
    lg0 += __shfl_xor(lg0, 1); lg1 += __shfl_xor(lg1, 1);
    lg2 += __shfl_xor(lg2, 1); lg3 += __shfl_xor(lg3, 1);
    float ce = 0.f, cc = 0.f;
    if (hf == 0) {
      float l0 = lg0 + b20, l1 = lg1 + b21, l2 = lg2 + b22, l3 = lg3 + b23;
      int t = etg;
      int am = 0; float mx = l0;
      if (l1 > mx) { mx = l1; am = 1; }
      if (l2 > mx) { mx = l2; am = 2; }
      if (l3 > mx) { mx = l3; am = 3; }
      float s = __expf(l0 - mx) + __expf(l1 - mx) + __expf(l2 - mx) + __expf(l3 - mx);
      float lt = (t == 0) ? l0 : (t == 1) ? l1 : (t == 2) ? l2 : l3;
      ce = __logf(s) + mx - lt;
      cc = (am == t) ? 1.f : 0.f;
    }
    #pragma unroll
    for (int d = 1; d < 64; d <<= 1) { ce += __shfl_xor(ce, d); cc += __shfl_xor(cc, d); }
    if (lane == 0) { s_red[w * 2] = ce; s_red[w * 2 + 1] = cc; }
    __syncthreads();
    if (tid == 0) {
      atomicAdd(accum + 0, s_red[0] + s_red[2] + s_red[4] + s_red[6]);
      atomicAdd(accum + 1, s_red[1] + s_red[3] + s_red[5] + s_red[7]);
    }
  }
}

// ---------------------------------------------------------------------------
// Atom head: 64 rows/block (4 blocks/CU), 4 waves x (64 rows x 64 cols) L1.
// LDS union: X/h bf16 [64][256] swz (32KB)  /  logits f32 [64][130] (33.3KB).
// ---------------------------------------------------------------------------
__global__ __launch_bounds__(256, 4) void k_atom(
    const float* __restrict__ node,
    const unsigned short* __restrict__ w1p, const float* __restrict__ b1,
    const unsigned short* __restrict__ w2p, const float* __restrict__ b2,
    const int* __restrict__ tgt, float* __restrict__ accum)
{
  __shared__ __align__(16) unsigned char sm[33280];
  __shared__ float s_red[8];
  const int tid = threadIdx.x;
  const int lane = tid & 63;
  const int w = tid >> 6;
  const int l31 = lane & 31;
  const int h = lane >> 5;
  const int swz = (l31 & 7) << 4;
  const int CW = w * 64;
  const long rowbase = (long)blockIdx.x * 64;

  STAGE_X(sm, node + rowbase * 256);
  __syncthreads();                 // staging visible

  f32x16 zero = {};
  f32x16 acc00, acc01, acc10, acc11;

  GEMM22(sm, w1p, CW);             // hidden pre-act
  __syncthreads();                 // all X reads done
  WB22(sm, acc00, 0, 0, CW, b1);
  WB22(sm, acc10, 0, 1, CW, b1);
  WB22(sm, acc01, 1, 0, CW, b1);
  WB22(sm, acc11, 1, 1, CW, b1);
  __syncthreads();                 // h visible

  // ---- layer 2: wave w -> cols w*32..+31 (of 128-pad), rows 0..63 ----
  f32x16 accL0 = zero, accL1 = zero;
  {
    const int cw2 = w * 32;
    const unsigned char* wb_ = (const unsigned char*)w2p +
                               ((cw2 + l31) << 5) + (h << 4);
    bf16x8 pB0 = *(const bf16x8*)BADDR(sm, 0, 0);
    bf16x8 pB1 = *(const bf16x8*)BADDR(sm, 1, 0);
    uint4 pA = *(const uint4*)(wb_);
    #pragma unroll
    for (int kk = 0; kk < 16; kk += 2) {
      bf16x8 qB0 = *(const bf16x8*)BADDR(sm, 0, kk + 1);
      bf16x8 qB1 = *(const bf16x8*)BADDR(sm, 1, kk + 1);
      uint4 qA = *(const uint4*)(wb_ + ((kk + 1) << 12));
      accL0 = mfma16(as_bf16x8(pA), pB0, accL0);
      accL1 = mfma16(as_bf16x8(pA), pB1, accL1);
      if (kk + 2 < 16) {
        pB0 = *(const bf16x8*)BADDR(sm, 0, kk + 2);
        pB1 = *(const bf16x8*)BADDR(sm, 1, kk + 2);
        pA = *(const uint4*)(wb_ + ((kk + 2) << 12));
      }
      accL0 = mfma16(as_bf16x8(qA), qB0, accL0);
      accL1 = mfma16(as_bf16x8(qA), qB1, accL1);
    }
  }
  __syncthreads();                 // all h reads done; sm reusable

  // ---- logits (f32, +bias) into lg[row][col], row stride 130 dwords ----
  {
    float* lgf = (float*)sm;
    const int cw2 = w * 32;
    #pragma unroll
    for (int q = 0; q < 16; ++q) {
      int col = cw2 + (q & 3) + 8 * (q >> 2) + 4 * h;
      if (col < 118) {
        float bv = b2[col];
        lgf[(l31) * 130 + col] = accL0[q] + bv;
        lgf[(32 + l31) * 130 + col] = accL1[q] + bv;
      }
    }
  }
  __syncthreads();                 // logits visible

  // ---- epilogue: 2 lanes per row (cols split 59/59), waves 0-1 ----
  float ce = 0.f, cc = 0.f;
  if (tid < 128) {
    const float* lgf = (const float*)sm;
    int row = tid >> 1, h2 = tid & 1;
    int t = tgt[rowbase + row];
    const float* lr = lgf + row * 130;
    int c0 = h2 * 59;
    float mx = -3.0e38f; int am = 127;
    for (int j = 0; j < 59; ++j) {
      float v = lr[c0 + j];
      if (v > mx) { mx = v; am = c0 + j; }
    }
    float mo = __shfl_xor(mx, 1); int amo = __shfl_xor(am, 1);
    if (mo > mx || (mo == mx && amo < am)) { mx = mo; am = amo; }
    float s = 0.f, vt = 0.f;
    for (int j = 0; j < 59; ++j) {
      float v = lr[c0 + j];
      s += __expf(v - mx);
      if (c0 + j == t) vt = v;
    }
    s += __shfl_xor(s, 1);
    vt += __shfl_xor(vt, 1);
    if (h2 == 0) {
      ce = __logf(s) + mx - vt;
      cc = (am == t) ? 1.f : 0.f;
    }
  }
  #pragma unroll
  for (int d = 1; d < 64; d <<= 1) { ce += __shfl_xor(ce, d); cc += __shfl_xor(cc, d); }
  if (lane == 0) { s_red[w * 2] = ce; s_red[w * 2 + 1] = cc; }
  __syncthreads();
  if (tid == 0) {
    atomicAdd(accum + 2, s_red[0] + s_red[2] + s_red[4] + s_red[6]);
    atomicAdd(accum + 3, s_red[1] + s_red[3] + s_red[5] + s_red[7]);
  }
}

__global__ __launch_bounds__(64) void k_final(const float* __restrict__ accum,
                                              float* __restrict__ out)
{
  if (threadIdx.x == 0) {
    float bce = accum[0] / 262144.f;
    float bcc = accum[1] / 262144.f;
    float ace = accum[2] / 131072.f;
    float acc_ = accum[3] / 131072.f;
    out[0] = 0.5f * bce + 0.5f * ace;
    out[1] = bcc;
    out[2] = acc_;
  }
}

extern "C" void kernel_launch(void* const* d_in, const int* in_sizes, int n_in,
                              void* d_out, int out_size, void* d_ws, size_t ws_size,
                              hipStream_t stream)
{
  const float* node = (const float*)d_in[0];
  const int* eidx   = (const int*)d_in[1];
  const int* btt    = (const int*)d_in[2];
  const int* att    = (const int*)d_in[3];
  const float* Wp1 = (const float*)d_in[4];
  const float* bp1 = (const float*)d_in[5];
  const float* Wp2 = (const float*)d_in[6];
  const float* bp2 = (const float*)d_in[7];
  const float* Wb1 = (const float*)d_in[8];
  const float* bb1 = (const float*)d_in[9];
  const float* Wb2 = (const float*)d_in[10];
  const float* bb2 = (const float*)d_in[11];
  const float* Wa1 = (const float*)d_in[12];
  const float* ba1 = (const float*)d_in[13];
  const float* Wa2 = (const float*)d_in[14];
  const float* ba2 = (const float*)d_in[15];

  char* ws = (char*)d_ws;
  float* accum = (float*)ws;
  unsigned short* dp1 = (unsigned short*)(ws + 256);
  unsigned short* da1 = (unsigned short*)(ws + 131328);
  unsigned short* da2 = (unsigned short*)(ws + 262400);
  unsigned short* dct = (unsigned short*)(ws + 327936);
  unsigned short* dcb = (unsigned short*)(ws + 459008);
  float* bias_e       = (float*)(ws + 590080);

  k_pack<<<640, 256, 0, stream>>>(Wp1, Wa1, Wa2, dp1, da1, da2, accum);
  k_fold<<<513, 256, 0, stream>>>(Wp2, Wb1, bp2, bb1, dct, dcb, bias_e);
  k_atom<<<2048, 256, 0, stream>>>(node, da1, ba1, da2, ba2, att, accum);
  k_bond<<<2048, 256, 0, stream>>>(node, eidx, btt, dp1, bp1, dct, dcb,
                                   bias_e, Wb2, bb2, accum);
  k_final<<<1, 64, 0, stream>>>(accum, (float*)d_out);
}

// Round 5
// 195.372 us; speedup vs baseline: 1.2601x; 1.2601x over previous
//
#include <hip/hip_runtime.h>
#include <hip/hip_bf16.h>

// M=2048, A=64, E=128, H=256, bond types=4, atom types=118
typedef __bf16 bf16x8 __attribute__((ext_vector_type(8)));
typedef float f32x16 __attribute__((ext_vector_type(16)));

__device__ inline unsigned short f2bf(float f) {
  __hip_bfloat16 h = __float2bfloat16(f);
  return *reinterpret_cast<unsigned short*>(&h);
}
__device__ inline unsigned pack2bf(float a, float b) {
  return (unsigned)f2bf(a) | ((unsigned)f2bf(b) << 16);
}
__device__ inline uint2 pack4bf(float a, float b, float c, float d) {
  uint2 r; r.x = pack2bf(a, b); r.y = pack2bf(c, d); return r;
}
__device__ inline bf16x8 as_bf16x8(uint4 v) { return __builtin_bit_cast(bf16x8, v); }
__device__ inline float bitf(unsigned u) { return __builtin_bit_cast(float, u); }
__device__ inline f32x16 mfma16(bf16x8 a, bf16x8 b, f32x16 c) {
  return __builtin_amdgcn_mfma_f32_32x32x16_bf16(a, b, c, 0, 0, 0);
}

// LDS addr of X/h element: row (R*32+l31), k-chunk KK, half h; XOR row-swizzle.
#define BADDR(XB, R, KK)                                                       \
  ((XB) + (((((R) * 32 + l31) << 9) + ((KK) << 5) + (h << 4)) ^ swz))

// 64-row x 64-col per-wave GEMM over K=256, depth-1 ping-pong prefetch,
// K-loop unrolling DISABLED (full unroll caused load-hoisting -> VGPR spill).
#define GEMM22(XB, WPTR, CW_)                                                  \
  {                                                                            \
    const unsigned char* wb_ = (const unsigned char*)(WPTR) +                  \
                               (((CW_) + l31) << 5) + (h << 4);                \
    acc00 = zero; acc01 = zero; acc10 = zero; acc11 = zero;                    \
    bf16x8 pB0 = *(const bf16x8*)BADDR(XB, 0, 0);                              \
    bf16x8 pB1 = *(const bf16x8*)BADDR(XB, 1, 0);                              \
    uint4 pA0 = *(const uint4*)(wb_ + 0);                                      \
    uint4 pA1 = *(const uint4*)(wb_ + 1024);                                   \
    _Pragma("clang loop unroll(disable)")                                      \
    for (int kk = 0; kk < 16; kk += 2) {                                       \
      bf16x8 qB0 = *(const bf16x8*)BADDR(XB, 0, kk + 1);                       \
      bf16x8 qB1 = *(const bf16x8*)BADDR(XB, 1, kk + 1);                       \
      uint4 qA0 = *(const uint4*)(wb_ + ((kk + 1) << 13));                     \
      uint4 qA1 = *(const uint4*)(wb_ + ((kk + 1) << 13) + 1024);              \
      acc00 = mfma16(as_bf16x8(pA0), pB0, acc00);                              \
      acc10 = mfma16(as_bf16x8(pA1), pB0, acc10);                              \
      acc01 = mfma16(as_bf16x8(pA0), pB1, acc01);                              \
      acc11 = mfma16(as_bf16x8(pA1), pB1, acc11);                              \
      if (kk + 2 < 16) {                                                       \
        pB0 = *(const bf16x8*)BADDR(XB, 0, kk + 2);                            \
        pB1 = *(const bf16x8*)BADDR(XB, 1, kk + 2);                            \
        pA0 = *(const uint4*)(wb_ + ((kk + 2) << 13));                         \
        pA1 = *(const uint4*)(wb_ + ((kk + 2) << 13) + 1024);                  \
      }                                                                        \
      acc00 = mfma16(as_bf16x8(qA0), qB0, acc00);                              \
      acc10 = mfma16(as_bf16x8(qA1), qB0, acc10);                              \
      acc01 = mfma16(as_bf16x8(qA0), qB1, acc01);                              \
      acc11 = mfma16(as_bf16x8(qA1), qB1, acc11);                              \
    }                                                                          \
  }

// write one 32x32 tile: rows (R*32+l31), cols (CW_+C*32..+31), bias+relu
#define WB22(DB, ACC, R, C, CW_, BIASPTR)                                      \
  _Pragma("unroll")                                                            \
  for (int g = 0; g < 4; ++g) {                                                \
    int xr_ = (R) * 32 + l31;                                                  \
    int col = (CW_) + (C) * 32 + g * 8 + h * 4;                                \
    float4 bb = *(const float4*)((BIASPTR) + col);                             \
    float v0 = fmaxf(ACC[4 * g + 0] + bb.x, 0.f);                              \
    float v1 = fmaxf(ACC[4 * g + 1] + bb.y, 0.f);                              \
    float v2 = fmaxf(ACC[4 * g + 2] + bb.z, 0.f);                              \
    float v3 = fmaxf(ACC[4 * g + 3] + bb.w, 0.f);                              \
    int off = ((xr_ << 9) + (col << 1)) ^ ((xr_ & 7) << 4);                    \
    *(uint2*)((DB) + off) = pack4bf(v0, v1, v2, v3);                           \
  }

#define WB22R(DB, ACC, R, C, CW_)                                              \
  _Pragma("unroll")                                                            \
  for (int g = 0; g < 4; ++g) {                                                \
    int xr_ = (R) * 32 + l31;                                                  \
    int col = (CW_) + (C) * 32 + g * 8 + h * 4;                                \
    int off = ((xr_ << 9) + (col << 1)) ^ ((xr_ & 7) << 4);                    \
    *(uint2*)((DB) + off) = pack4bf(ACC[4 * g + 0], ACC[4 * g + 1],            \
                                    ACC[4 * g + 2], ACC[4 * g + 3]);           \
  }

// f32 staging: 64x256 f32 -> bf16 LDS, row-swizzled
#define STAGE_X(DST, SRC)                                                      \
  _Pragma("unroll")                                                            \
  for (int it = 0; it < 8; ++it) {                                             \
    int lb = (it * 256 + tid) * 16;                                            \
    int d_ = lb ^ (((lb >> 9) & 7) << 4);                                      \
    const float4* s4 = (const float4*)((SRC) + (lb >> 1));                     \
    float4 f0 = s4[0], f1 = s4[1];                                             \
    uint4 v_ = { pack2bf(f0.x, f0.y), pack2bf(f0.z, f0.w),                     \
                 pack2bf(f1.x, f1.y), pack2bf(f1.z, f1.w) };                   \
    *(uint4*)((DST) + d_) = v_;                                                \
  }

// ---------------------------------------------------------------------------
// Pack Wp1 / Wa1 / Wa2 to bf16 fragment layout: ushort[(kk*N + n)*16 + dk]
// ---------------------------------------------------------------------------
__global__ __launch_bounds__(256) void k_pack(
    const float* __restrict__ wp1, const float* __restrict__ wa1,
    const float* __restrict__ wa2,
    unsigned short* __restrict__ dp1, unsigned short* __restrict__ da1,
    unsigned short* __restrict__ da2, float* __restrict__ accum)
{
  int b = blockIdx.x, tid = threadIdx.x;
  if (b == 0 && tid < 8) accum[tid] = 0.f;
  const float* src; unsigned short* dst; int e, logN, Nreal;
  if (b < 256)       { src = wp1; dst = dp1; e = b * 256 + tid;          logN = 8; Nreal = 256; }
  else if (b < 512)  { src = wa1; dst = da1; e = (b - 256) * 256 + tid;  logN = 8; Nreal = 256; }
  else               { src = wa2; dst = da2; e = (b - 512) * 256 + tid;  logN = 7; Nreal = 118; }
  int dk = e & 15;
  int rest = e >> 4;
  int n = rest & ((1 << logN) - 1);
  int kk = rest >> logN;
  int k = kk * 16 + dk;
  float v = (n < Nreal) ? src[k * Nreal + n] : 0.f;
  dst[e] = f2bf(v);
}

// ---------------------------------------------------------------------------
// Fold: Wct = Wp2 @ Wb1[0:256,:], Wcb = Wp2 @ Wb1[256:512,:]  (packed bf16)
//       bias_e = bp2 @ (Wb1t+Wb1b) + bb1
// ---------------------------------------------------------------------------
__global__ __launch_bounds__(256) void k_fold(
    const float* __restrict__ wp2, const float* __restrict__ wb1,
    const float* __restrict__ bp2, const float* __restrict__ bb1,
    unsigned short* __restrict__ dct, unsigned short* __restrict__ dcb,
    float* __restrict__ bias_e)
{
  int b = blockIdx.x, n = threadIdx.x;
  if (b < 512) {
    int k = b & 255;
    int off = (b < 256) ? 0 : 256;
    float s = 0.f;
    for (int t = 0; t < 256; ++t)
      s += wp2[k * 256 + t] * wb1[(t + off) * 256 + n];
    unsigned short* dst = (b < 256) ? dct : dcb;
    dst[((k >> 4) * 256 + n) * 16 + (k & 15)] = f2bf(s);
  } else {
    float s = bb1[n];
    for (int t = 0; t < 256; ++t)
      s += bp2[t] * (wb1[t * 256 + n] + wb1[(256 + t) * 256 + n]);
    bias_e[n] = s;
  }
}

// ---------------------------------------------------------------------------
// Fused per-molecule kernel: atom head + bond head, X staged once.
// bufA: X -> hs ;  bufB: ha -> logits(f32) -> h1 -> he.
// ---------------------------------------------------------------------------
__global__ __launch_bounds__(256, 2) void k_mol(
    const float* __restrict__ node, const int* __restrict__ eidx,
    const int* __restrict__ btt, const int* __restrict__ att,
    const unsigned short* __restrict__ wp1p, const float* __restrict__ bp1,
    const unsigned short* __restrict__ wctp, const unsigned short* __restrict__ wcbp,
    const float* __restrict__ bias_e, const float* __restrict__ wb2,
    const float* __restrict__ bb2,
    const unsigned short* __restrict__ wa1p, const float* __restrict__ ba1,
    const unsigned short* __restrict__ wa2p, const float* __restrict__ ba2,
    float* __restrict__ accum)
{
  __shared__ __align__(16) unsigned char bufA[32768];
  __shared__ __align__(16) unsigned char bufB[32768];
  __shared__ float s_bias[256];
  __shared__ float4 s_wb2[256];
  __shared__ float s_b2a[128];
  __shared__ float s_red[8];
  const int tid = threadIdx.x;
  const int lane = tid & 63;
  const int w = tid >> 6;
  const int l31 = lane & 31;
  const int h = lane >> 5;
  const int swz = (l31 & 7) << 4;
  const int CW = w * 64;
  const int m = blockIdx.x;

  STAGE_X(bufA, node + (long)m * 16384);
  s_bias[tid] = bias_e[tid];
  s_wb2[tid] = ((const float4*)wb2)[tid];
  if (tid < 128) s_b2a[tid] = (tid < 118) ? ba2[tid] : 0.f;
  __syncthreads();                 // b1: staging visible

  f32x16 zero = {};
  f32x16 acc00, acc01, acc10, acc11;

  // ===== atom head =====
  GEMM22(bufA, wa1p, CW);          // ha pre-act (reads X=bufA)
  WB22(bufB, acc00, 0, 0, CW, ba1);
  WB22(bufB, acc10, 0, 1, CW, ba1);
  WB22(bufB, acc01, 1, 0, CW, ba1);
  WB22(bufB, acc11, 1, 1, CW, ba1);
  __syncthreads();                 // b2: ha visible

  // atom layer 2: wave w -> cols w*32..+31 (of 128-pad), rows 0..63
  f32x16 accL0 = zero, accL1 = zero;
  {
    const int cw2 = w * 32;
    const unsigned char* wb_ = (const unsigned char*)wa2p +
                               ((cw2 + l31) << 5) + (h << 4);
    bf16x8 pB0 = *(const bf16x8*)BADDR(bufB, 0, 0);
    bf16x8 pB1 = *(const bf16x8*)BADDR(bufB, 1, 0);
    uint4 pA = *(const uint4*)(wb_);
    _Pragma("clang loop unroll(disable)")
    for (int kk = 0; kk < 16; kk += 2) {
      bf16x8 qB0 = *(const bf16x8*)BADDR(bufB, 0, kk + 1);
      bf16x8 qB1 = *(const bf16x8*)BADDR(bufB, 1, kk + 1);
      uint4 qA = *(const uint4*)(wb_ + ((kk + 1) << 12));
      accL0 = mfma16(as_bf16x8(pA), pB0, accL0);
      accL1 = mfma16(as_bf16x8(pA), pB1, accL1);
      if (kk + 2 < 16) {
        pB0 = *(const bf16x8*)BADDR(bufB, 0, kk + 2);
        pB1 = *(const bf16x8*)BADDR(bufB, 1, kk + 2);
        pA = *(const uint4*)(wb_ + ((kk + 2) << 12));
      }
      accL0 = mfma16(as_bf16x8(qA), qB0, accL0);
      accL1 = mfma16(as_bf16x8(qA), qB1, accL1);
    }
  }
  __syncthreads();                 // b3: all ha reads done; bufB reusable

  // logits (f32, +ba2) -> bufB, row-swizzled (row stride 512B)
  {
    const int cw2 = w * 32;
    #pragma unroll
    for (int q = 0; q < 16; ++q) {
      int col = cw2 + (q & 3) + 8 * (q >> 2) + 4 * h;
      if (col < 118) {
        float bv = s_b2a[col];
        int r0 = l31, r1 = 32 + l31;
        *(float*)(bufB + ((r0 << 9) + (((col << 2)) ^ ((r0 & 7) << 4)))) = accL0[q] + bv;
        *(float*)(bufB + ((r1 << 9) + (((col << 2)) ^ ((r1 & 7) << 4)))) = accL1[q] + bv;
      }
    }
  }
  __syncthreads();                 // b4: logits visible

  // atom epilogue: 4 lanes per row, cols split 30/30/30/28
  {
    const int row = tid >> 2, g4 = tid & 3;
    const int t = att[m * 64 + row];
    const unsigned char* lr = bufB + (row << 9);
    const int rswz = (row & 7) << 4;
    const int c0 = g4 * 30;
    const int cend = (g4 == 3) ? 118 : c0 + 30;
    float mx = -3.0e38f; int am = 127;
    for (int c = c0; c < cend; ++c) {
      float v = *(const float*)(lr + (((c << 2)) ^ rswz));
      if (v > mx) { mx = v; am = c; }
    }
    float mo = __shfl_xor(mx, 1); int amo = __shfl_xor(am, 1);
    if (mo > mx || (mo == mx && amo < am)) { mx = mo; am = amo; }
    mo = __shfl_xor(mx, 2); amo = __shfl_xor(am, 2);
    if (mo > mx || (mo == mx && amo < am)) { mx = mo; am = amo; }
    float s = 0.f, vt = 0.f;
    for (int c = c0; c < cend; ++c) {
      float v = *(const float*)(lr + (((c << 2)) ^ rswz));
      s += __expf(v - mx);
      if (c == t) vt = v;
    }
    s += __shfl_xor(s, 1); s += __shfl_xor(s, 2);
    vt += __shfl_xor(vt, 1); vt += __shfl_xor(vt, 2);
    float ce = 0.f, cc = 0.f;
    if (g4 == 0) { ce = __logf(s) + mx - vt; cc = (am == t) ? 1.f : 0.f; }
    #pragma unroll
    for (int d = 1; d < 64; d <<= 1) { ce += __shfl_xor(ce, d); cc += __shfl_xor(cc, d); }
    if (lane == 0) { s_red[w * 2] = ce; s_red[w * 2 + 1] = cc; }
  }
  __syncthreads();                 // b5: epilogue done, bufB free
  if (tid == 0) {
    atomicAdd(accum + 2, s_red[0] + s_red[2] + s_red[4] + s_red[6]);
    atomicAdd(accum + 3, s_red[1] + s_red[3] + s_red[5] + s_red[7]);
  }

  // ===== bond head =====
  GEMM22(bufA, wp1p, CW);          // h1 pre-act (reads X=bufA)
  WB22(bufB, acc00, 0, 0, CW, bp1);
  WB22(bufB, acc10, 0, 1, CW, bp1);
  WB22(bufB, acc01, 1, 0, CW, bp1);
  WB22(bufB, acc11, 1, 1, CW, bp1);
  __syncthreads();                 // b6: h1 visible; all X reads done

  GEMM22(bufB, wctp, CW);          // hs (reads h1=bufB)
  WB22R(bufA, acc00, 0, 0, CW);    // hs over X (safe: b6 passed)
  WB22R(bufA, acc10, 0, 1, CW);
  WB22R(bufA, acc01, 1, 0, CW);
  WB22R(bufA, acc11, 1, 1, CW);
  GEMM22(bufB, wcbp, CW);          // he (in regs)
  // edge metadata: issue now, drains during b7's barrier
  const int es = eidx[m * 256 + (tid >> 1)];
  const int ed = eidx[m * 256 + 128 + (tid >> 1)];
  const int etg = btt[m * 128 + (tid >> 1)];
  const float b20 = bb2[0], b21 = bb2[1], b22 = bb2[2], b23 = bb2[3];
  __syncthreads();                 // b7: all h1 reads done
  WB22R(bufB, acc00, 0, 0, CW);    // he over h1
  WB22R(bufB, acc10, 0, 1, CW);
  WB22R(bufB, acc01, 1, 0, CW);
  WB22R(bufB, acc11, 1, 1, CW);
  __syncthreads();                 // b8: hs/he visible

  // edge phase: thread pair (2t,2t+1) -> edge t, col-halves. hs=bufA, he=bufB
  {
    const int hf = tid & 1;
    float lg0 = 0.f, lg1 = 0.f, lg2 = 0.f, lg3 = 0.f;
    #pragma unroll
    for (int j = 0; j < 16; ++j) {
      int c0 = hf * 128 + j * 8;
      int offS = ((es << 9) + (c0 << 1)) ^ ((es & 7) << 4);
      int offD = ((ed << 9) + (c0 << 1)) ^ ((ed & 7) << 4);
      uint4 us = *(const uint4*)(bufA + offS);
      uint4 ud = *(const uint4*)(bufB + offD);
      const unsigned* pu = (const unsigned*)&us;
      const unsigned* pv = (const unsigned*)&ud;
      #pragma unroll
      for (int q = 0; q < 4; ++q) {
        unsigned ua = pu[q], ub = pv[q];
        int c = c0 + 2 * q;
        float hlo = bitf(ua << 16) + bitf(ub << 16) + s_bias[c];
        float hhi = bitf(ua & 0xffff0000u) + bitf(ub & 0xffff0000u) + s_bias[c + 1];
        hlo = fmaxf(hlo, 0.f); hhi = fmaxf(hhi, 0.f);
        float4 w0 = s_wb2[c], w1 = s_wb2[c + 1];
        lg0 = fmaf(hlo, w0.x, fmaf(hhi, w1.x, lg0));
        lg1 = fmaf(hlo, w0.y, fmaf(hhi, w1.y, lg1));
        lg2 = fmaf(hlo, w0.z, fmaf(hhi, w1.z, lg2));
        lg3 = fmaf(hlo, w0.w, fmaf(hhi, w1.w, lg3));
      }
    }
    lg0 += __shfl_xor(lg0, 1); lg1 += __shfl_xor(lg1, 1);
    lg2 += __shfl_xor(lg2, 1); lg3 += __shfl_xor(lg3, 1);
    float ce = 0.f, cc = 0.f;
    if (hf == 0) {
      float l0 = lg0 + b20, l1 = lg1 + b21, l2 = lg2 + b22, l3 = lg3 + b23;
      int t = etg;
      int am = 0; float mx = l0;
      if (l1 > mx) { mx = l1; am = 1; }
      if (l2 > mx) { mx = l2; am = 2; }
      if (l3 > mx) { mx = l3; am = 3; }
      float s = __expf(l0 - mx) + __expf(l1 - mx) + __expf(l2 - mx) + __expf(l3 - mx);
      float lt = (t == 0) ? l0 : (t == 1) ? l1 : (t == 2) ? l2 : l3;
      ce = __logf(s) + mx - lt;
      cc = (am == t) ? 1.f : 0.f;
    }
    #pragma unroll
    for (int d = 1; d < 64; d <<= 1) { ce += __shfl_xor(ce, d); cc += __shfl_xor(cc, d); }
    if (lane == 0) { s_red[w * 2] = ce; s_red[w * 2 + 1] = cc; }
    __syncthreads();
    if (tid == 0) {
      atomicAdd(accum + 0, s_red[0] + s_red[2] + s_red[4] + s_red[6]);
      atomicAdd(accum + 1, s_red[1] + s_red[3] + s_red[5] + s_red[7]);
    }
  }
}

__global__ __launch_bounds__(64) void k_final(const float* __restrict__ accum,
                                              float* __restrict__ out)
{
  if (threadIdx.x == 0) {
    float bce = accum[0] / 262144.f;
    float bcc = accum[1] / 262144.f;
    float ace = accum[2] / 131072.f;
    float acc_ = accum[3] / 131072.f;
    out[0] = 0.5f * bce + 0.5f * ace;
    out[1] = bcc;
    out[2] = acc_;
  }
}

extern "C" void kernel_launch(void* const* d_in, const int* in_sizes, int n_in,
                              void* d_out, int out_size, void* d_ws, size_t ws_size,
                              hipStream_t stream)
{
  const float* node = (const float*)d_in[0];
  const int* eidx   = (const int*)d_in[1];
  const int* btt    = (const int*)d_in[2];
  const int* att    = (const int*)d_in[3];
  const float* Wp1 = (const float*)d_in[4];
  const float* bp1 = (const float*)d_in[5];
  const float* Wp2 = (const float*)d_in[6];
  const float* bp2 = (const float*)d_in[7];
  const float* Wb1 = (const float*)d_in[8];
  const float* bb1 = (const float*)d_in[9];
  const float* Wb2 = (const float*)d_in[10];
  const float* bb2 = (const float*)d_in[11];
  const float* Wa1 = (const float*)d_in[12];
  const float* ba1 = (const float*)d_in[13];
  const float* Wa2 = (const float*)d_in[14];
  const float* ba2 = (const float*)d_in[15];

  char* ws = (char*)d_ws;
  float* accum = (float*)ws;
  unsigned short* dp1 = (unsigned short*)(ws + 256);
  unsigned short* da1 = (unsigned short*)(ws + 131328);
  unsigned short* da2 = (unsigned short*)(ws + 262400);
  unsigned short* dct = (unsigned short*)(ws + 327936);
  unsigned short* dcb = (unsigned short*)(ws + 459008);
  float* bias_e       = (float*)(ws + 590080);

  k_pack<<<640, 256, 0, stream>>>(Wp1, Wa1, Wa2, dp1, da1, da2, accum);
  k_fold<<<513, 256, 0, stream>>>(Wp2, Wb1, bp2, bb1, dct, dcb, bias_e);
  k_mol<<<2048, 256, 0, stream>>>(node, eidx, btt, att, dp1, bp1, dct, dcb,
                                  bias_e, Wb2, bb2, da1, ba1, da2, ba2, accum);
  k_final<<<1, 64, 0, stream>>>(accum, (float*)d_out);
}